// Round 6
// baseline (199.956 us; speedup 1.0000x reference)
//
#include <hip/hip_runtime.h>
#include <math.h>

#define BB 4
#define CC 256
#define NN 4096
#define DQ 32
#define LOG2E 1.44269504f

typedef _Float16 half8 __attribute__((ext_vector_type(8)));
typedef _Float16 half4 __attribute__((ext_vector_type(4)));
typedef float float4v __attribute__((ext_vector_type(4)));

// ---------------- prep: W -> f16 (log2e folded into Wq/bq) ----------------
__global__ __launch_bounds__(64) void prep_kernel(
    const float* __restrict__ Wq, const float* __restrict__ bq,
    const float* __restrict__ Wk, const float* __restrict__ bk,
    const float* __restrict__ Wv, const float* __restrict__ bv,
    _Float16* __restrict__ Wh, float* __restrict__ bh)
{
    int o = blockIdx.x, t = threadIdx.x;
    const float* src; float scale = 1.0f, bias;
    if (o < DQ)            { src = Wq + o * CC;        scale = LOG2E; bias = bq[o] * LOG2E; }
    else if (o < 2 * DQ)   { src = Wk + (o - DQ) * CC;                bias = bk[o - DQ]; }
    else                   { src = Wv + (o - 2 * DQ) * CC;            bias = bv[o - 2 * DQ]; }
    float4 v = *(const float4*)(src + t * 4);
    half4 h = { (_Float16)(v.x * scale), (_Float16)(v.y * scale),
                (_Float16)(v.z * scale), (_Float16)(v.w * scale) };
    *(half4*)(Wh + o * CC + t * 4) = h;
    if (t == 0) bh[o] = bias;
}

// ---------------- proj: MFMA GEMM, all 320 outputs x 32-pixel tile ----------------
__global__ __launch_bounds__(256) void proj_kernel(
    const float* __restrict__ x, const _Float16* __restrict__ Wh,
    const float* __restrict__ bh,
    _Float16* __restrict__ Qt, _Float16* __restrict__ Kt,
    _Float16* __restrict__ Vh)
{
    __shared__ _Float16 xl[32 * 256];
    __shared__ _Float16 os_qk[32 * 72];
    __shared__ _Float16 os_v[256 * 40];

    const int tid = threadIdx.x;
    const int lane = tid & 63, w = tid >> 6;
    const int i16 = lane & 15, q = lane >> 4;
    const int n0 = blockIdx.x * 32, b = blockIdx.y;

    const float* xb = x + (size_t)b * CC * NN + n0;
    #pragma unroll
    for (int u = 0; u < 8; ++u) {
        int idx = u * 256 + tid;
        int c = idx >> 3, n4 = idx & 7;
        float4 v = *(const float4*)(xb + (size_t)c * NN + n4 * 4);
        int chunk = c >> 3, cl = c & 7;
        float vv[4] = {v.x, v.y, v.z, v.w};
        #pragma unroll
        for (int e = 0; e < 4; ++e) {
            int n = n4 * 4 + e;
            xl[n * 256 + ((chunk ^ n) * 8) + cl] = (_Float16)vv[e];
        }
    }

    float4v acc[5][2];
    const int obase = 80 * w;
    #pragma unroll
    for (int ot = 0; ot < 5; ++ot) {
        float4 b4 = *(const float4*)(bh + obase + 16 * ot + 4 * q);
        #pragma unroll
        for (int nt = 0; nt < 2; ++nt)
            acc[ot][nt] = (float4v){b4.x, b4.y, b4.z, b4.w};
    }
    __syncthreads();

    #pragma unroll
    for (int k = 0; k < 8; ++k) {
        half8 af[5], bf[2];
        #pragma unroll
        for (int ot = 0; ot < 5; ++ot)
            af[ot] = *(const half8*)(Wh + (size_t)(obase + 16 * ot + i16) * CC + k * 32 + 8 * q);
        #pragma unroll
        for (int nt = 0; nt < 2; ++nt) {
            int n = 16 * nt + i16;
            bf[nt] = *(const half8*)&xl[n * 256 + (((4 * k + q) ^ n) * 8)];
        }
        #pragma unroll
        for (int ot = 0; ot < 5; ++ot)
            #pragma unroll
            for (int nt = 0; nt < 2; ++nt)
                acc[ot][nt] = __builtin_amdgcn_mfma_f32_16x16x32_f16(af[ot], bf[nt], acc[ot][nt], 0, 0, 0);
    }

    #pragma unroll
    for (int ot = 0; ot < 5; ++ot) {
        int og = obase + 16 * ot;
        #pragma unroll
        for (int nt = 0; nt < 2; ++nt) {
            int n = 16 * nt + i16;
            if (og < 64) {
                half4 hv = { (_Float16)acc[ot][nt][0], (_Float16)acc[ot][nt][1],
                             (_Float16)acc[ot][nt][2], (_Float16)acc[ot][nt][3] };
                *(half4*)&os_qk[n * 72 + og + 4 * q] = hv;
            } else {
                int cb = og - 64 + 4 * q;
                #pragma unroll
                for (int r = 0; r < 4; ++r)
                    os_v[(cb + r) * 40 + n] = (_Float16)acc[ot][nt][r];
            }
        }
    }
    __syncthreads();

    _Float16* Qtb = Qt + (size_t)b * NN * DQ;
    _Float16* Ktb = Kt + (size_t)b * NN * DQ;
    {
        int n = tid >> 3, p = tid & 7;
        half8 hv = *(const half8*)&os_qk[n * 72 + 8 * p];
        if (p < 4) *(half8*)(Qtb + (size_t)(n0 + n) * DQ + 8 * p) = hv;
        else       *(half8*)(Ktb + (size_t)(n0 + n) * DQ + 8 * (p - 4)) = hv;
    }
    _Float16* Vb = Vh + (size_t)b * CC * NN;
    #pragma unroll
    for (int u = 0; u < 4; ++u) {
        int c = u * 64 + (tid >> 2), p = tid & 3;
        half8 hv = *(const half8*)&os_v[c * 40 + 8 * p];
        *(half8*)(Vb + (size_t)c * NN + n0 + 8 * p) = hv;
    }
}

// ---------------- attn: 32q x 128c blocks, KVBLK=32, 4 blocks/CU ----------------
// Grid (128,2,4) = 1024 blocks = 4/CU (LDS 33.5KB). Pass M: max-only prepass,
// 4-deep K prefetch. Main loop: r3-verified 1-barrier pipeline (S(t)->ps[t&1],
// PV(t-1) from ps/v of t-1, stage t+1, prefetch t+2). Paired-row XOR LDS
// layouts: elem(row,chunk g) at (row>>1)*64 + 8*((g+4*(row&1))^((row>>1)&7))
// -> all b128 reads/writes <=2-way bank aliasing (free).
// Wave roles: S: j-strip 16*(w&1), query-half ih=w>>1 (1 MFMA + 4 exp2/iter);
// PV: c in [32w,32w+32), 4 MFMA/iter. l accumulated from f32 P' inline.
__global__ __launch_bounds__(256) void attn_kernel(
    const float* __restrict__ x,
    const _Float16* __restrict__ Qt, const _Float16* __restrict__ Kt,
    const _Float16* __restrict__ Vh,
    float* __restrict__ out)
{
    __shared__ _Float16 k2[2][16 * 64];    // K tile, paired-row swizzle
    __shared__ _Float16 v2[3][64 * 64];    // V tile, paired-row swizzle
    __shared__ _Float16 ps[2][32 * 40];    // P': [i][j + pad8]
    __shared__ float    stx[4][32];        // cross-wave exchange (m, then l)

    const int tid = threadIdx.x;
    const int w = tid >> 6, lane = tid & 63;
    const int i16 = lane & 15, q = lane >> 4;
    const int i0 = blockIdx.x * 32, cs = blockIdx.y, b = blockIdx.z;
    const int c0 = cs * 128;

    const _Float16* Ktb = Kt + (size_t)b * NN * DQ;
    const _Float16* Vb  = Vh + (size_t)b * CC * NN + (size_t)c0 * NN;

    half8 qb[2];
    {
        const _Float16* Qtb = Qt + (size_t)b * NN * DQ;
        qb[0] = *(const half8*)(Qtb + (size_t)(i0 + i16) * DQ + 8 * q);
        qb[1] = *(const half8*)(Qtb + (size_t)(i0 + 16 + i16) * DQ + 8 * q);
    }

    // ---- pass M: per-query max over this wave's key quarter (no exp2) ----
    float mA[2] = {-INFINITY, -INFINITY};
    {
        const _Float16* kq = Ktb + (size_t)(1024 * w) * DQ;
        half8 kf[4];
        #pragma unroll
        for (int u = 0; u < 4; ++u)
            kf[u] = *(const half8*)(kq + (size_t)(16 * u + i16) * DQ + 8 * q);
        for (int t = 0; t < 64; t += 4) {
            #pragma unroll
            for (int u = 0; u < 4; ++u) {
                half8 ka = kf[u];
                int nt = t + 4 + u;
                if (nt < 64)
                    kf[u] = *(const half8*)(kq + (size_t)(16 * nt + i16) * DQ + 8 * q);
                float4v z = {0.f, 0.f, 0.f, 0.f};
                float4v s0 = __builtin_amdgcn_mfma_f32_16x16x32_f16(ka, qb[0], z, 0, 0, 0);
                float4v s1 = __builtin_amdgcn_mfma_f32_16x16x32_f16(ka, qb[1], z, 0, 0, 0);
                mA[0] = fmaxf(mA[0], fmaxf(fmaxf(s0[0], s0[1]), fmaxf(s0[2], s0[3])));
                mA[1] = fmaxf(mA[1], fmaxf(fmaxf(s1[0], s1[1]), fmaxf(s1[2], s1[3])));
            }
        }
        #pragma unroll
        for (int it = 0; it < 2; ++it) {
            mA[it] = fmaxf(mA[it], __shfl_xor(mA[it], 16, 64));
            mA[it] = fmaxf(mA[it], __shfl_xor(mA[it], 32, 64));
        }
        if (q == 0) { stx[w][i16] = mA[0]; stx[w][16 + i16] = mA[1]; }
    }
    __syncthreads();

    float m2v[2];
    #pragma unroll
    for (int it = 0; it < 2; ++it) {
        int r = 16 * it + i16;
        m2v[it] = fmaxf(fmaxf(stx[0][r], stx[1][r]), fmaxf(stx[2][r], stx[3][r]));
    }

    // ---- main loop setup ----
    float4v O[2][2];
    #pragma unroll
    for (int ct = 0; ct < 2; ++ct)
        #pragma unroll
        for (int it = 0; it < 2; ++it)
            O[ct][it] = (float4v){0.f, 0.f, 0.f, 0.f};
    float lB = 0.f;

    // staging indices: K (tid<128, waves 0-1): 1 half8; V (all): 2 half8
    const int jK = (tid & 127) >> 2, dgK = tid & 3;
    const int kaddr = (jK >> 1) * 64 + (((dgK + 4 * (jK & 1)) ^ ((jK >> 1) & 7)) * 8);
    const int cV = tid >> 2, jgV = tid & 3;
    int vaddr[2];
    #pragma unroll
    for (int u = 0; u < 2; ++u) {
        int c = 64 * u + cV;
        vaddr[u] = (c >> 1) * 64 + (((jgV + 4 * (c & 1)) ^ ((c >> 1) & 7)) * 8);
    }
    // read offsets
    const int jS = 16 * (w & 1) + i16;
    const int ka_off = (jS >> 1) * 64 + (((q + 4 * (jS & 1)) ^ ((jS >> 1) & 7)) * 8);
    const int ih = w >> 1;
    int va_off[2];
    #pragma unroll
    for (int ct = 0; ct < 2; ++ct) {
        int c = 32 * w + 16 * ct + i16;
        va_off[ct] = (c >> 1) * 64 + (((q + 4 * (c & 1)) ^ ((c >> 1) & 7)) * 8);
    }
    const int pswr = (16 * ih + i16) * 40 + 16 * (w & 1) + 4 * q;
    const int pb_off0 = i16 * 40 + 8 * q;
    const int pb_off1 = (16 + i16) * 40 + 8 * q;

    // prologue: tile 0 -> buffers 0; tile 1 in regs
    half8 kv, vv[2];
    if (w < 2) kv = *(const half8*)(Ktb + (size_t)jK * DQ + 8 * dgK);
    #pragma unroll
    for (int u = 0; u < 2; ++u)
        vv[u] = *(const half8*)(Vb + (size_t)(64 * u + cV) * NN + 8 * jgV);
    if (w < 2) *(half8*)&k2[0][kaddr] = kv;
    #pragma unroll
    for (int u = 0; u < 2; ++u)
        *(half8*)&v2[0][vaddr[u]] = vv[u];
    if (w < 2) kv = *(const half8*)(Ktb + (size_t)(32 + jK) * DQ + 8 * dgK);
    #pragma unroll
    for (int u = 0; u < 2; ++u)
        vv[u] = *(const half8*)(Vb + (size_t)(64 * u + cV) * NN + 32 + 8 * jgV);

    for (int t = 0; t <= 128; ++t) {
        __syncthreads();
        // stage tile t+1 from regs
        if (t < 127) {
            if (w < 2) *(half8*)&k2[(t + 1) & 1][kaddr] = kv;
            const int vn = (t + 1) % 3;
            #pragma unroll
            for (int u = 0; u < 2; ++u)
                *(half8*)&v2[vn][vaddr[u]] = vv[u];
        }
        // issue prefetch of tile t+2
        if (t < 126) {
            int jn = (t + 2) * 32;
            if (w < 2) kv = *(const half8*)(Ktb + (size_t)(jn + jK) * DQ + 8 * dgK);
            #pragma unroll
            for (int u = 0; u < 2; ++u)
                vv[u] = *(const half8*)(Vb + (size_t)(64 * u + cV) * NN + jn + 8 * jgV);
        }
        // PV(t-1): inputs completed before this iter's barrier
        if (t > 0) {
            const _Float16* psp = ps[(t - 1) & 1];
            const _Float16* vp  = v2[(t - 1) % 3];
            half8 pbv0 = *(const half8*)&psp[pb_off0];
            half8 pbv1 = *(const half8*)&psp[pb_off1];
            half8 va0  = *(const half8*)&vp[va_off[0]];
            half8 va1  = *(const half8*)&vp[va_off[1]];
            __builtin_amdgcn_s_setprio(1);
            O[0][0] = __builtin_amdgcn_mfma_f32_16x16x32_f16(va0, pbv0, O[0][0], 0, 0, 0);
            O[0][1] = __builtin_amdgcn_mfma_f32_16x16x32_f16(va0, pbv1, O[0][1], 0, 0, 0);
            O[1][0] = __builtin_amdgcn_mfma_f32_16x16x32_f16(va1, pbv0, O[1][0], 0, 0, 0);
            O[1][1] = __builtin_amdgcn_mfma_f32_16x16x32_f16(va1, pbv1, O[1][1], 0, 0, 0);
            __builtin_amdgcn_s_setprio(0);
        }
        // S(t) -> ps[t&1]; accumulate l from f32 P'
        if (t < 128) {
            half8 ka = *(const half8*)&k2[t & 1][ka_off];
            float4v z = {0.f, 0.f, 0.f, 0.f};
            float4v s = __builtin_amdgcn_mfma_f32_16x16x32_f16(ka, qb[ih], z, 0, 0, 0);
            float p0 = exp2f(s[0] - m2v[ih]);
            float p1 = exp2f(s[1] - m2v[ih]);
            float p2 = exp2f(s[2] - m2v[ih]);
            float p3 = exp2f(s[3] - m2v[ih]);
            lB += (p0 + p1) + (p2 + p3);
            half4 hv = { (_Float16)p0, (_Float16)p1, (_Float16)p2, (_Float16)p3 };
            *(half4*)&ps[t & 1][pswr] = hv;
        }
    }

    // reduce l: over q-quads, then across the two waves sharing a query-half
    lB += __shfl_xor(lB, 16, 64);
    lB += __shfl_xor(lB, 32, 64);
    if (q == 0) stx[w][i16] = lB;
    __syncthreads();
    float linv[2];
    #pragma unroll
    for (int it = 0; it < 2; ++it)
        linv[it] = 1.0f / (stx[2 * it][i16] + stx[2 * it + 1][i16]);

    // epilogue: O * (1/l) + residual
    const float* xb = x + (size_t)b * CC * NN;
    float* ob = out + (size_t)b * CC * NN;
    #pragma unroll
    for (int ct = 0; ct < 2; ++ct)
        #pragma unroll
        for (int it = 0; it < 2; ++it)
            #pragma unroll
            for (int r = 0; r < 4; ++r) {
                int c = c0 + 32 * w + 16 * ct + 4 * q + r;
                size_t idx = (size_t)c * NN + i0 + 16 * it + i16;
                ob[idx] = xb[idx] + O[ct][it][r] * linv[it];
            }
}

extern "C" void kernel_launch(void* const* d_in, const int* in_sizes, int n_in,
                              void* d_out, int out_size, void* d_ws, size_t ws_size,
                              hipStream_t stream) {
    const float* x  = (const float*)d_in[0];
    const float* Wq = (const float*)d_in[1];
    const float* bq = (const float*)d_in[2];
    const float* Wk = (const float*)d_in[3];
    const float* bk = (const float*)d_in[4];
    const float* Wv = (const float*)d_in[5];
    const float* bv = (const float*)d_in[6];
    float* out = (float*)d_out;

    char* ws = (char*)d_ws;
    _Float16* Wh = (_Float16*)(ws);                 // 320*256*2 = 163840
    float*    bh = (float*)(ws + 163840);           // 1280
    _Float16* Qt = (_Float16*)(ws + 262144);        // 4*4096*32*2 = 1 MB
    _Float16* Kt = (_Float16*)(ws + 1310720);       // 1 MB
    _Float16* Vh = (_Float16*)(ws + 2359296);       // 4*256*4096*2 = 8 MB

    prep_kernel<<<dim3(320), 64, 0, stream>>>(Wq, bq, Wk, bk, Wv, bv, Wh, bh);
    proj_kernel<<<dim3(NN / 32, BB), 256, 0, stream>>>(x, Wh, bh, Qt, Kt, Vh);
    attn_kernel<<<dim3(NN / 32, 2, BB), 256, 0, stream>>>(x, Qt, Kt, Vh, out);
}